// Round 1
// baseline (408.026 us; speedup 1.0000x reference)
//
#include <hip/hip_runtime.h>
#include <cstdint>
#include <cstddef>

typedef __bf16 bf16;
typedef bf16 bf16x8 __attribute__((ext_vector_type(8)));
typedef float f32x4 __attribute__((ext_vector_type(4)));

#define DEVI __device__ __forceinline__

// ---------------- constants ----------------
// B=4, T=2048, D=1152, H=8, HD=144, BT=8192
#define CB 4
#define CT 2048
#define CD 1152
#define CH 8
#define CHD 144
#define CBT 8192

DEVI void gload_lds16(const void* g, void* l) {
  __builtin_amdgcn_global_load_lds(
      (const __attribute__((address_space(1))) void*)g,
      (__attribute__((address_space(3))) void*)l, 16, 0, 0);
}

DEVI f32x4 mfma16(bf16x8 a, bf16x8 b, f32x4 c) {
  return __builtin_amdgcn_mfma_f32_16x16x32_bf16(a, b, c, 0, 0, 0);
}

// ---------------- cast f32 -> bf16 (8 els / thread) ----------------
__global__ __launch_bounds__(256) void k_cast(const float* __restrict__ in,
                                              bf16* __restrict__ out, int n8) {
  int i = blockIdx.x * 256 + threadIdx.x;
  if (i >= n8) return;
  const float4* p = (const float4*)in + (size_t)i * 2;
  float4 a = p[0], b = p[1];
  bf16x8 o;
  o[0] = (bf16)a.x; o[1] = (bf16)a.y; o[2] = (bf16)a.z; o[3] = (bf16)a.w;
  o[4] = (bf16)b.x; o[5] = (bf16)b.y; o[6] = (bf16)b.z; o[7] = (bf16)b.w;
  ((bf16x8*)out)[i] = o;
}

// ---------------- zero page (1 KiB) ----------------
__global__ void k_zero(float4* zp) {
  float4 z; z.x = z.y = z.z = z.w = 0.f;
  zp[threadIdx.x] = z;
}

// ---------------- GEMM C[M,N] = A[M,K] * W[N,K]^T  (bf16 in, f32 acc) ----------------
// 128x128 tile, BK=32, 4 waves (2x2), 16x16x32 MFMA. LDS rows padded to 40 els.
template <bool BF16_OUT>
DEVI void gemm_body(const bf16* __restrict__ A, const bf16* __restrict__ W,
                    void* __restrict__ Cout, int M, int N, int K) {
  __shared__ __align__(16) bf16 As[128 * 40];
  __shared__ __align__(16) bf16 Bs[128 * 40];
  const int tid = threadIdx.x;
  const int lane = tid & 63, wid = tid >> 6;
  const int l15 = lane & 15, g = lane >> 4;
  const int wm = wid >> 1, wn = wid & 1;
  const int bm0 = blockIdx.y * 128, bn0 = blockIdx.x * 128;

  f32x4 acc[4][4];
  for (int mi = 0; mi < 4; ++mi)
    for (int ni = 0; ni < 4; ++ni) {
      acc[mi][ni][0] = 0.f; acc[mi][ni][1] = 0.f;
      acc[mi][ni][2] = 0.f; acc[mi][ni][3] = 0.f;
    }

  const int nk = K >> 5;
  for (int kt = 0; kt < nk; ++kt) {
    const int k0 = kt << 5;
    // stage A and B tiles: 128 rows x 32 cols (pad to 40), 640 lane-loads each
    for (int c = 0; c < 3; ++c) {
      int li = tid + (c << 8);
      if (li < 640) {
        int e0 = li << 3;
        int row = e0 / 40, col = e0 % 40;
        if (col >= 32) col = 24;  // pad cols never read as fragments
        gload_lds16(&A[(size_t)(bm0 + row) * K + k0 + col], As + (size_t)(li & ~63) * 8);
        gload_lds16(&W[(size_t)(bn0 + row) * K + k0 + col], Bs + (size_t)(li & ~63) * 8);
      }
    }
    __syncthreads();

    bf16x8 af[4], bfr[4];
    for (int mi = 0; mi < 4; ++mi)
      af[mi] = *(const bf16x8*)&As[(wm * 64 + mi * 16 + l15) * 40 + g * 8];
    for (int ni = 0; ni < 4; ++ni)
      bfr[ni] = *(const bf16x8*)&Bs[(wn * 64 + ni * 16 + l15) * 40 + g * 8];
    for (int mi = 0; mi < 4; ++mi)
      for (int ni = 0; ni < 4; ++ni)
        acc[mi][ni] = mfma16(af[mi], bfr[ni], acc[mi][ni]);
    __syncthreads();
  }

  // epilogue: C row = (l>>4)*4 + r, col = l&15  [m89 layout]
  for (int mi = 0; mi < 4; ++mi)
    for (int ni = 0; ni < 4; ++ni)
      for (int r = 0; r < 4; ++r) {
        int rowg = bm0 + wm * 64 + mi * 16 + g * 4 + r;
        int colg = bn0 + wn * 64 + ni * 16 + l15;
        float v = acc[mi][ni][r];
        if (BF16_OUT)
          ((bf16*)Cout)[(size_t)rowg * N + colg] = (bf16)v;
        else
          ((float*)Cout)[(size_t)rowg * N + colg] = v;
      }
}

__global__ __launch_bounds__(256) void k_gemm_qkv(
    const bf16* __restrict__ A, const bf16* __restrict__ Wq,
    const bf16* __restrict__ Wk, const bf16* __restrict__ Wv,
    bf16* __restrict__ q, bf16* __restrict__ k, bf16* __restrict__ v) {
  const bf16* W = (blockIdx.z == 0) ? Wq : (blockIdx.z == 1) ? Wk : Wv;
  bf16* out = (blockIdx.z == 0) ? q : (blockIdx.z == 1) ? k : v;
  gemm_body<true>(A, W, out, CBT, CD, CD);
}

__global__ __launch_bounds__(256) void k_gemm_out(
    const bf16* __restrict__ A, const bf16* __restrict__ W, float* __restrict__ out) {
  gemm_body<false>(A, W, out, CBT, CD, CD);
}

// ---------------- rotary, in place on q_lin/k_lin [b][t][h*144+hd] ----------------
__global__ __launch_bounds__(256) void k_rotary(bf16* __restrict__ q, bf16* __restrict__ k,
                                                const float* __restrict__ cosb,
                                                const float* __restrict__ sinb) {
  const int bt = blockIdx.x;
  const int t = bt & (CT - 1);
  const size_t rowoff = (size_t)bt * CD;
  const float* cr = cosb + (size_t)t * CHD;
  const float* sr = sinb + (size_t)t * CHD;
  for (int i = threadIdx.x; i < 1152; i += 256) {
    int tensor = i / 576;
    int p = i % 576;
    int h = p / 72, j = p % 72;
    bf16* base = (tensor ? k : q) + rowoff + h * CHD;
    float a = (float)base[j];
    float b2 = (float)base[j + 72];
    float o1 = a * cr[j] - b2 * sr[j];
    float o2 = b2 * cr[j + 72] + a * sr[j + 72];
    base[j] = (bf16)o1;
    base[j + 72] = (bf16)o2;
  }
}

// ---------------- V transpose: v_lin[b][t][h*144+hd] -> vT[bh][hd][t] ----------------
__global__ __launch_bounds__(256) void k_vtrans(const bf16* __restrict__ v, bf16* __restrict__ vT) {
  __shared__ bf16 tile[64][152];  // 304B stride: 16B-aligned rows, spread banks
  const int bh = blockIdx.y;
  const int b = bh >> 3, h = bh & 7;
  const int t0 = blockIdx.x * 64;
  for (int i8 = threadIdx.x; i8 < 64 * 18; i8 += 256) {
    int r = i8 / 18, c8 = i8 % 18;
    *(bf16x8*)&tile[r][c8 * 8] =
        *(const bf16x8*)&v[((size_t)(b * CT + t0 + r)) * CD + h * CHD + c8 * 8];
  }
  __syncthreads();
  for (int o = threadIdx.x; o < CHD * 64; o += 256) {
    int hd = o / 64, j = o & 63;
    vT[((size_t)(bh * CHD + hd)) * CT + t0 + j] = tile[j][hd];
  }
}

// ---------------- flash attention ----------------
// grid: (T/64, B*H). 4 waves x 16 q-rows. KV tile = 64.
// K LDS padded: hd 144 -> 160 zeros (5 uniform K=32 MFMA steps), row stride 168.
// Vt LDS [144][72] (keys padded 64->72). P per-wave [16][72].
__global__ __launch_bounds__(256) void k_attn(const bf16* __restrict__ qg,
                                              const bf16* __restrict__ kg,
                                              const bf16* __restrict__ vT,
                                              bf16* __restrict__ og,
                                              const void* __restrict__ zp) {
  const int bh = blockIdx.y;
  const int b = bh >> 3, h = bh & 7;
  const int q0 = blockIdx.x << 6;
  const int tid = threadIdx.x, lane = tid & 63, wid = tid >> 6;
  const int l15 = lane & 15, g = lane >> 4;

  __shared__ __align__(16) bf16 Ks[64 * 168];
  __shared__ __align__(16) bf16 Vs[144 * 72];
  __shared__ __align__(16) bf16 Ps[4][16 * 72];

  bf16x8 zero8;
  for (int i = 0; i < 8; ++i) zero8[i] = (bf16)0.f;

  // q fragments: A-layout row=l15, k=(g*8 + kk*32)
  bf16x8 qf[5];
  {
    const bf16* qbase = qg + (size_t)(b * CT + q0 + wid * 16 + l15) * CD + h * CHD;
    for (int kk = 0; kk < 5; ++kk) {
      int k0 = kk * 32 + g * 8;
      qf[kk] = (k0 < CHD) ? *(const bf16x8*)&qbase[k0] : zero8;
    }
  }

  f32x4 oacc[9];
  for (int n = 0; n < 9; ++n) { oacc[n][0] = 0.f; oacc[n][1] = 0.f; oacc[n][2] = 0.f; oacc[n][3] = 0.f; }
  float mrow[4] = {-__builtin_inff(), -__builtin_inff(), -__builtin_inff(), -__builtin_inff()};
  float lsum[4] = {0.f, 0.f, 0.f, 0.f};
  const float sc = 0.083333333333f * 1.44269504089f;  // SCALE * log2(e)

  for (int kv = 0; kv < CT; kv += 64) {
    // stage K tile: 64 x 168 els = 1344 lane-loads
    for (int c = 0; c < 6; ++c) {
      int li = tid + (c << 8);
      if (li < 1344) {
        int e0 = li << 3;
        int row = e0 / 168, col = e0 % 168;
        const void* src = (col < CHD)
            ? (const void*)(kg + (size_t)(b * CT + kv + row) * CD + h * CHD + col)
            : zp;
        gload_lds16(src, Ks + (size_t)(li & ~63) * 8);
      }
    }
    // stage Vt tile: 144 x 72 els = 1296 lane-loads
    for (int c = 0; c < 6; ++c) {
      int li = tid + (c << 8);
      if (li < 1296) {
        int e0 = li << 3;
        int row = e0 / 72, col = e0 % 72;
        const void* src = (col < 64)
            ? (const void*)(vT + (size_t)(bh * CHD + row) * CT + kv + col)
            : zp;
        gload_lds16(src, Vs + (size_t)(li & ~63) * 8);
      }
    }
    __syncthreads();

    // S = q * K^T   (rows: 16 q, cols: 64 keys -> 4 n-tiles)
    f32x4 s[4];
    for (int j = 0; j < 4; ++j) { s[j][0] = 0.f; s[j][1] = 0.f; s[j][2] = 0.f; s[j][3] = 0.f; }
    for (int kk = 0; kk < 5; ++kk)
      for (int j = 0; j < 4; ++j) {
        bf16x8 kf = *(const bf16x8*)&Ks[(j * 16 + l15) * 168 + kk * 32 + g * 8];
        s[j] = mfma16(qf[kk], kf, s[j]);
      }
    for (int j = 0; j < 4; ++j) s[j] = s[j] * sc;  // now in log2 units

    // online softmax: row r_global = g*4 + r; reduce across the 16 lanes (l&15)
    for (int r = 0; r < 4; ++r) {
      float v = fmaxf(fmaxf(s[0][r], s[1][r]), fmaxf(s[2][r], s[3][r]));
      for (int d = 1; d < 16; d <<= 1) v = fmaxf(v, __shfl_xor(v, d));
      float mnew = fmaxf(mrow[r], v);
      float alpha = exp2f(mrow[r] - mnew);
      mrow[r] = mnew;
      float psum = 0.f;
      for (int j = 0; j < 4; ++j) {
        float p = exp2f(s[j][r] - mnew);
        psum += p;
        Ps[wid][(g * 4 + r) * 72 + j * 16 + l15] = (bf16)p;
      }
      lsum[r] = lsum[r] * alpha + psum;
      for (int n = 0; n < 9; ++n) oacc[n][r] *= alpha;
    }

    // PV: o += P(16x64) * Vt^T  -> A from Ps, B from Vs (B^T form)
    bf16x8 pa[2];
    for (int kk = 0; kk < 2; ++kk)
      pa[kk] = *(const bf16x8*)&Ps[wid][l15 * 72 + kk * 32 + g * 8];
    for (int n = 0; n < 9; ++n)
      for (int kk = 0; kk < 2; ++kk) {
        bf16x8 vb = *(const bf16x8*)&Vs[(n * 16 + l15) * 72 + kk * 32 + g * 8];
        oacc[n] = mfma16(pa[kk], vb, oacc[n]);
      }
    __syncthreads();
  }

  // normalize + store
  float inv[4];
  for (int r = 0; r < 4; ++r) {
    float t = lsum[r];
    for (int d = 1; d < 16; d <<= 1) t += __shfl_xor(t, d);
    inv[r] = 1.0f / t;
  }
  bf16* obase = og + (size_t)(b * CT + q0 + wid * 16) * CD + h * CHD;
  for (int n = 0; n < 9; ++n)
    for (int r = 0; r < 4; ++r)
      obase[(size_t)(g * 4 + r) * CD + n * 16 + l15] = (bf16)(oacc[n][r] * inv[r]);
}

// ---------------- launcher ----------------
extern "C" void kernel_launch(void* const* d_in, const int* in_sizes, int n_in,
                              void* d_out, int out_size, void* d_ws, size_t ws_size,
                              hipStream_t stream) {
  const float* x = (const float*)d_in[0];
  const float* cosb = (const float*)d_in[1];
  const float* sinb = (const float*)d_in[2];
  const float* Wq = (const float*)d_in[3];
  const float* Wk = (const float*)d_in[4];
  const float* Wv = (const float*)d_in[5];
  const float* Wo = (const float*)d_in[6];

  char* ws = (char*)d_ws;
  // sizes: xb/o_bt 18,874,368 ; each W 2,654,208 ; q/k/v_lin 18,874,368 ; vT 18,874,368
  bf16* xb   = (bf16*)(ws + 0);           // reused as attention output (o_bt)
  bf16* wqb  = (bf16*)(ws + 18874368);
  bf16* wkb  = (bf16*)(ws + 21528576);
  bf16* wvb  = (bf16*)(ws + 24182784);
  bf16* wob  = (bf16*)(ws + 26836992);
  bf16* qlin = (bf16*)(ws + 29491200);
  bf16* klin = (bf16*)(ws + 48365568);
  bf16* vlin = (bf16*)(ws + 67239936);
  bf16* vT   = (bf16*)(ws + 86114304);
  void* zp   = (void*)(ws + 104988672);   // 1 KiB zero page

  k_zero<<<1, 64, 0, stream>>>((float4*)zp);

  // casts
  k_cast<<<4608, 256, 0, stream>>>(x, xb, CBT * CD / 8);
  k_cast<<<648, 256, 0, stream>>>(Wq, wqb, CD * CD / 8);
  k_cast<<<648, 256, 0, stream>>>(Wk, wkb, CD * CD / 8);
  k_cast<<<648, 256, 0, stream>>>(Wv, wvb, CD * CD / 8);
  k_cast<<<648, 256, 0, stream>>>(Wo, wob, CD * CD / 8);

  // QKV projections (fused over blockIdx.z)
  k_gemm_qkv<<<dim3(CD / 128, CBT / 128, 3), 256, 0, stream>>>(xb, wqb, wkb, wvb,
                                                               qlin, klin, vlin);
  // rotary in place on q,k
  k_rotary<<<CB * CT, 256, 0, stream>>>(qlin, klin, cosb, sinb);
  // V transpose
  k_vtrans<<<dim3(CT / 64, CB * CH), 256, 0, stream>>>(vlin, vT);
  // attention -> o (into xb region, [b][t][h*144+hd])
  k_attn<<<dim3(CT / 64, CB * CH), 256, 0, stream>>>(qlin, klin, vT, xb, zp);
  // output projection (f32 out)
  k_gemm_out<<<dim3(CD / 128, CBT / 128), 256, 0, stream>>>(xb, wob, (float*)d_out);
}

// Round 2
// 379.078 us; speedup vs baseline: 1.0764x; 1.0764x over previous
//
#include <hip/hip_runtime.h>
#include <cstdint>
#include <cstddef>

typedef __bf16 bf16;
typedef bf16 bf16x8 __attribute__((ext_vector_type(8)));
typedef bf16 bf16x4 __attribute__((ext_vector_type(4)));
typedef float f32x4 __attribute__((ext_vector_type(4)));

#define DEVI __device__ __forceinline__

// ---------------- constants ----------------
// B=4, T=2048, D=1152, H=8, HD=144, BT=8192
#define CB 4
#define CT 2048
#define CD 1152
#define CH 8
#define CHD 144
#define CBT 8192

DEVI void gload_lds16(const void* g, void* l) {
  __builtin_amdgcn_global_load_lds(
      (const __attribute__((address_space(1))) void*)g,
      (__attribute__((address_space(3))) void*)l, 16, 0, 0);
}

DEVI f32x4 mfma16(bf16x8 a, bf16x8 b, f32x4 c) {
  return __builtin_amdgcn_mfma_f32_16x16x32_bf16(a, b, c, 0, 0, 0);
}

// ---------------- cast f32 -> bf16 (8 els / thread) ----------------
__global__ __launch_bounds__(256) void k_cast(const float* __restrict__ in,
                                              bf16* __restrict__ out, int n8) {
  int i = blockIdx.x * 256 + threadIdx.x;
  if (i >= n8) return;
  const float4* p = (const float4*)in + (size_t)i * 2;
  float4 a = p[0], b = p[1];
  bf16x8 o;
  o[0] = (bf16)a.x; o[1] = (bf16)a.y; o[2] = (bf16)a.z; o[3] = (bf16)a.w;
  o[4] = (bf16)b.x; o[5] = (bf16)b.y; o[6] = (bf16)b.z; o[7] = (bf16)b.w;
  ((bf16x8*)out)[i] = o;
}

// ---------------- zero page (1 KiB) ----------------
__global__ void k_zero(float4* zp) {
  float4 z; z.x = z.y = z.z = z.w = 0.f;
  zp[threadIdx.x] = z;
}

// ---------------- GEMM C[M,N] = A[M,K] * W[N,K]^T  (bf16 in, f32 acc) ----------------
// 128x128 tile, BK=32, 4 waves (2x2), 16x16x32 MFMA. LDS rows padded to 40 els.
template <bool BF16_OUT>
DEVI void gemm_body(const bf16* __restrict__ A, const bf16* __restrict__ W,
                    void* __restrict__ Cout, int M, int N, int K) {
  __shared__ __align__(16) bf16 As[128 * 40];
  __shared__ __align__(16) bf16 Bs[128 * 40];
  const int tid = threadIdx.x;
  const int lane = tid & 63, wid = tid >> 6;
  const int l15 = lane & 15, g = lane >> 4;
  const int wm = wid >> 1, wn = wid & 1;
  const int bm0 = blockIdx.y * 128, bn0 = blockIdx.x * 128;

  f32x4 acc[4][4];
  for (int mi = 0; mi < 4; ++mi)
    for (int ni = 0; ni < 4; ++ni) {
      acc[mi][ni][0] = 0.f; acc[mi][ni][1] = 0.f;
      acc[mi][ni][2] = 0.f; acc[mi][ni][3] = 0.f;
    }

  const int nk = K >> 5;
  for (int kt = 0; kt < nk; ++kt) {
    const int k0 = kt << 5;
    // stage A and B tiles: 128 rows x 32 cols (pad to 40), 640 lane-loads each
    for (int c = 0; c < 3; ++c) {
      int li = tid + (c << 8);
      if (li < 640) {
        int e0 = li << 3;
        int row = e0 / 40, col = e0 % 40;
        if (col >= 32) col = 24;  // pad cols never read as fragments
        gload_lds16(&A[(size_t)(bm0 + row) * K + k0 + col], As + (size_t)(li & ~63) * 8);
        gload_lds16(&W[(size_t)(bn0 + row) * K + k0 + col], Bs + (size_t)(li & ~63) * 8);
      }
    }
    __syncthreads();

    bf16x8 af[4], bfr[4];
    for (int mi = 0; mi < 4; ++mi)
      af[mi] = *(const bf16x8*)&As[(wm * 64 + mi * 16 + l15) * 40 + g * 8];
    for (int ni = 0; ni < 4; ++ni)
      bfr[ni] = *(const bf16x8*)&Bs[(wn * 64 + ni * 16 + l15) * 40 + g * 8];
    for (int mi = 0; mi < 4; ++mi)
      for (int ni = 0; ni < 4; ++ni)
        acc[mi][ni] = mfma16(af[mi], bfr[ni], acc[mi][ni]);
    __syncthreads();
  }

  // epilogue: C row = (l>>4)*4 + r, col = l&15  [m89 layout]
  for (int mi = 0; mi < 4; ++mi)
    for (int ni = 0; ni < 4; ++ni)
      for (int r = 0; r < 4; ++r) {
        int rowg = bm0 + wm * 64 + mi * 16 + g * 4 + r;
        int colg = bn0 + wn * 64 + ni * 16 + l15;
        float v = acc[mi][ni][r];
        if (BF16_OUT)
          ((bf16*)Cout)[(size_t)rowg * N + colg] = (bf16)v;
        else
          ((float*)Cout)[(size_t)rowg * N + colg] = v;
      }
}

__global__ __launch_bounds__(256) void k_gemm_qkv(
    const bf16* __restrict__ A, const bf16* __restrict__ Wq,
    const bf16* __restrict__ Wk, const bf16* __restrict__ Wv,
    bf16* __restrict__ q, bf16* __restrict__ k, bf16* __restrict__ v) {
  const bf16* W = (blockIdx.z == 0) ? Wq : (blockIdx.z == 1) ? Wk : Wv;
  bf16* out = (blockIdx.z == 0) ? q : (blockIdx.z == 1) ? k : v;
  gemm_body<true>(A, W, out, CBT, CD, CD);
}

__global__ __launch_bounds__(256) void k_gemm_out(
    const bf16* __restrict__ A, const bf16* __restrict__ W, float* __restrict__ out) {
  gemm_body<false>(A, W, out, CBT, CD, CD);
}

// ---------------- rotary, in place on q_lin/k_lin [b][t][h*144+hd] ----------------
// vectorized: 4 consecutive j per unit; 288 units per (b,t) row
__global__ __launch_bounds__(256) void k_rotary(bf16* __restrict__ q, bf16* __restrict__ k,
                                                const float* __restrict__ cosb,
                                                const float* __restrict__ sinb) {
  const int bt = blockIdx.x;
  const int t = bt & (CT - 1);
  const size_t rowoff = (size_t)bt * CD;
  const float* cr = cosb + (size_t)t * CHD;
  const float* sr = sinb + (size_t)t * CHD;
  for (int i = threadIdx.x; i < 288; i += 256) {
    int tensor = i / 144;
    int rem = i - tensor * 144;
    int h = rem / 18, jg = rem % 18;
    int j = jg * 4;
    bf16* base = (tensor ? k : q) + rowoff + h * CHD;
    bf16x4 a = *(bf16x4*)&base[j];
    bf16x4 b2 = *(bf16x4*)&base[j + 72];
    f32x4 c1 = *(const f32x4*)&cr[j];
    f32x4 s1 = *(const f32x4*)&sr[j];
    f32x4 c2 = *(const f32x4*)&cr[j + 72];
    f32x4 s2 = *(const f32x4*)&sr[j + 72];
    bf16x4 o1, o2;
    for (int r = 0; r < 4; ++r) {
      float av = (float)a[r], bv = (float)b2[r];
      o1[r] = (bf16)(av * c1[r] - bv * s1[r]);
      o2[r] = (bf16)(bv * c2[r] + av * s2[r]);
    }
    *(bf16x4*)&base[j] = o1;
    *(bf16x4*)&base[j + 72] = o2;
  }
}

// ---------------- V transpose: v_lin[b][t][h*144+hd] -> vT[bh][hd][t] ----------------
__global__ __launch_bounds__(256) void k_vtrans(const bf16* __restrict__ v, bf16* __restrict__ vT) {
  __shared__ bf16 tile[64][152];
  const int bh = blockIdx.y;
  const int b = bh >> 3, h = bh & 7;
  const int t0 = blockIdx.x * 64;
  for (int i8 = threadIdx.x; i8 < 64 * 18; i8 += 256) {
    int r = i8 / 18, c8 = i8 % 18;
    *(bf16x8*)&tile[r][c8 * 8] =
        *(const bf16x8*)&v[((size_t)(b * CT + t0 + r)) * CD + h * CHD + c8 * 8];
  }
  __syncthreads();
  for (int o = threadIdx.x; o < CHD * 64; o += 256) {
    int hd = o / 64, j = o & 63;
    vT[((size_t)(bh * CHD + hd)) * CT + t0 + j] = tile[j][hd];
  }
}

// ---------------- flash attention (swapped-operand form) ----------------
// grid: (T/64, B*H). 4 waves x 16 q-rows. KV tile = 64.
// S^T = mfma(K-frag, Q-frag): C row=key(g*4+r), col=q(l15) -> softmax lane-local.
// O^T = mfma(V^T-frag, P^T-frag): C row=hd, col=q -> rescale is scalar/lane.
// K LDS: hd 144 -> 160 zero-padded (5 uniform K=32 steps), row stride 168.
// Vt LDS [144][72]. P per-wave [16 q][72 keys] written as packed b64.
__global__ __launch_bounds__(256) void k_attn(const bf16* __restrict__ qg,
                                              const bf16* __restrict__ kg,
                                              const bf16* __restrict__ vT,
                                              bf16* __restrict__ og,
                                              const void* __restrict__ zp) {
  const int bh = blockIdx.y;
  const int b = bh >> 3, h = bh & 7;
  const int q0 = blockIdx.x << 6;
  const int tid = threadIdx.x, lane = tid & 63, wid = tid >> 6;
  const int l15 = lane & 15, g = lane >> 4;

  __shared__ __align__(16) bf16 Ks[64 * 168];
  __shared__ __align__(16) bf16 Vs[144 * 72];
  __shared__ __align__(16) bf16 Ps[4][16 * 72];

  bf16x8 zero8;
  for (int i = 0; i < 8; ++i) zero8[i] = (bf16)0.f;

  // Q as B-fragment: lane holds Q[q=l15][k=kk*32+g*8 ..]
  bf16x8 qf[5];
  {
    const bf16* qbase = qg + (size_t)(b * CT + q0 + wid * 16 + l15) * CD + h * CHD;
    for (int kk = 0; kk < 5; ++kk) {
      int k0 = kk * 32 + g * 8;
      qf[kk] = (k0 < CHD) ? *(const bf16x8*)&qbase[k0] : zero8;
    }
  }

  f32x4 oacc[9];
  for (int n = 0; n < 9; ++n) { oacc[n][0] = 0.f; oacc[n][1] = 0.f; oacc[n][2] = 0.f; oacc[n][3] = 0.f; }
  float mrow = -__builtin_inff();
  float lsum = 0.f;
  const float sc = 0.083333333333f * 1.44269504089f;  // SCALE * log2(e)

  for (int kv = 0; kv < CT; kv += 64) {
    // stage K tile: 64 x 168 els = 1344 lane-loads
    for (int c = 0; c < 6; ++c) {
      int li = tid + (c << 8);
      if (li < 1344) {
        int e0 = li << 3;
        int row = e0 / 168, col = e0 % 168;
        const void* src = (col < CHD)
            ? (const void*)(kg + (size_t)(b * CT + kv + row) * CD + h * CHD + col)
            : zp;
        gload_lds16(src, Ks + (size_t)(li & ~63) * 8);
      }
    }
    // stage Vt tile: 144 x 72 els = 1296 lane-loads
    for (int c = 0; c < 6; ++c) {
      int li = tid + (c << 8);
      if (li < 1296) {
        int e0 = li << 3;
        int row = e0 / 72, col = e0 % 72;
        const void* src = (col < 64)
            ? (const void*)(vT + (size_t)(bh * CHD + row) * CT + kv + col)
            : zp;
        gload_lds16(src, Vs + (size_t)(li & ~63) * 8);
      }
    }
    __syncthreads();

    // S^T = K * Q^T : rows=keys (4 j-tiles of 16), cols=16 q
    f32x4 s[4];
    for (int j = 0; j < 4; ++j) { s[j][0] = 0.f; s[j][1] = 0.f; s[j][2] = 0.f; s[j][3] = 0.f; }
    for (int kk = 0; kk < 5; ++kk)
      for (int j = 0; j < 4; ++j) {
        bf16x8 kf = *(const bf16x8*)&Ks[(j * 16 + l15) * 168 + kk * 32 + g * 8];
        s[j] = mfma16(kf, qf[kk], s[j]);
      }
    for (int j = 0; j < 4; ++j) s[j] = s[j] * sc;  // log2 units

    // online softmax: lane owns 16 scores of q-row l15 (keys j*16+g*4+r)
    float mt = -__builtin_inff();
    for (int j = 0; j < 4; ++j)
      for (int r = 0; r < 4; ++r) mt = fmaxf(mt, s[j][r]);
    mt = fmaxf(mt, __shfl_xor(mt, 16));
    mt = fmaxf(mt, __shfl_xor(mt, 32));
    float mnew = fmaxf(mrow, mt);
    float alpha = exp2f(mrow - mnew);
    mrow = mnew;

    float ps = 0.f;
    for (int j = 0; j < 4; ++j) {
      bf16x4 pb;
      for (int r = 0; r < 4; ++r) {
        float p = exp2f(s[j][r] - mnew);
        ps += p;
        pb[r] = (bf16)p;
      }
      *(bf16x4*)&Ps[wid][l15 * 72 + j * 16 + g * 4] = pb;  // row-major P[q][key]
    }
    lsum = lsum * alpha + ps;
    for (int n = 0; n < 9; ++n) oacc[n] = oacc[n] * alpha;

    // O^T += V^T * P^T : A-frag from Vs[hd][key], B-frag from Ps[q][key]
    for (int kk = 0; kk < 2; ++kk) {
      bf16x8 pa = *(const bf16x8*)&Ps[wid][l15 * 72 + kk * 32 + g * 8];
      for (int n = 0; n < 9; ++n) {
        bf16x8 vb = *(const bf16x8*)&Vs[(n * 16 + l15) * 72 + kk * 32 + g * 8];
        oacc[n] = mfma16(vb, pa, oacc[n]);
      }
    }
    __syncthreads();
  }

  // final: sum l across g, normalize, packed store (lane's q-row = l15)
  float lt = lsum;
  lt += __shfl_xor(lt, 16);
  lt += __shfl_xor(lt, 32);
  float inv = 1.0f / lt;
  bf16* obase = og + (size_t)(b * CT + q0 + wid * 16 + l15) * CD + h * CHD;
  for (int n = 0; n < 9; ++n) {
    bf16x4 ov;
    for (int r = 0; r < 4; ++r) ov[r] = (bf16)(oacc[n][r] * inv);
    *(bf16x4*)&obase[n * 16 + g * 4] = ov;
  }
}

// ---------------- launcher ----------------
extern "C" void kernel_launch(void* const* d_in, const int* in_sizes, int n_in,
                              void* d_out, int out_size, void* d_ws, size_t ws_size,
                              hipStream_t stream) {
  const float* x = (const float*)d_in[0];
  const float* cosb = (const float*)d_in[1];
  const float* sinb = (const float*)d_in[2];
  const float* Wq = (const float*)d_in[3];
  const float* Wk = (const float*)d_in[4];
  const float* Wv = (const float*)d_in[5];
  const float* Wo = (const float*)d_in[6];

  char* ws = (char*)d_ws;
  bf16* xb   = (bf16*)(ws + 0);           // reused as attention output (o_bt)
  bf16* wqb  = (bf16*)(ws + 18874368);
  bf16* wkb  = (bf16*)(ws + 21528576);
  bf16* wvb  = (bf16*)(ws + 24182784);
  bf16* wob  = (bf16*)(ws + 26836992);
  bf16* qlin = (bf16*)(ws + 29491200);
  bf16* klin = (bf16*)(ws + 48365568);
  bf16* vlin = (bf16*)(ws + 67239936);
  bf16* vT   = (bf16*)(ws + 86114304);
  void* zp   = (void*)(ws + 104988672);   // 1 KiB zero page

  k_zero<<<1, 64, 0, stream>>>((float4*)zp);

  // casts
  k_cast<<<4608, 256, 0, stream>>>(x, xb, CBT * CD / 8);
  k_cast<<<648, 256, 0, stream>>>(Wq, wqb, CD * CD / 8);
  k_cast<<<648, 256, 0, stream>>>(Wk, wkb, CD * CD / 8);
  k_cast<<<648, 256, 0, stream>>>(Wv, wvb, CD * CD / 8);
  k_cast<<<648, 256, 0, stream>>>(Wo, wob, CD * CD / 8);

  // QKV projections (fused over blockIdx.z)
  k_gemm_qkv<<<dim3(CD / 128, CBT / 128, 3), 256, 0, stream>>>(xb, wqb, wkb, wvb,
                                                               qlin, klin, vlin);
  // rotary in place on q,k
  k_rotary<<<CB * CT, 256, 0, stream>>>(qlin, klin, cosb, sinb);
  // V transpose
  k_vtrans<<<dim3(CT / 64, CB * CH), 256, 0, stream>>>(vlin, vT);
  // attention -> o (into xb region, [b][t][h*144+hd])
  k_attn<<<dim3(CT / 64, CB * CH), 256, 0, stream>>>(qlin, klin, vT, xb, zp);
  // output projection (f32 out)
  k_gemm_out<<<dim3(CD / 128, CBT / 128), 256, 0, stream>>>(xb, wob, (float*)d_out);
}

// Round 3
// 322.628 us; speedup vs baseline: 1.2647x; 1.1750x over previous
//
#include <hip/hip_runtime.h>
#include <cstdint>
#include <cstddef>

typedef __bf16 bf16;
typedef bf16 bf16x8 __attribute__((ext_vector_type(8)));
typedef bf16 bf16x4 __attribute__((ext_vector_type(4)));
typedef bf16 bf16x2 __attribute__((ext_vector_type(2)));
typedef float f32x4 __attribute__((ext_vector_type(4)));
typedef float f32x16 __attribute__((ext_vector_type(16)));
typedef uint32_t u32x2 __attribute__((ext_vector_type(2)));
typedef uint32_t u32x4 __attribute__((ext_vector_type(4)));

#define DEVI __device__ __forceinline__

// ---------------- constants ----------------
// B=4, T=2048, D=1152, H=8, HD=144, BT=8192
#define CB 4
#define CT 2048
#define CD 1152
#define CH 8
#define CHD 144
#define CBT 8192
#define LOG2E 1.44269504f

DEVI void gload_lds16(const void* g, void* l) {
  __builtin_amdgcn_global_load_lds(
      (const __attribute__((address_space(1))) void*)g,
      (__attribute__((address_space(3))) void*)l, 16, 0, 0);
}

DEVI f32x4 mfma16(bf16x8 a, bf16x8 b, f32x4 c) {
  return __builtin_amdgcn_mfma_f32_16x16x32_bf16(a, b, c, 0, 0, 0);
}
DEVI f32x16 mfma32(bf16x8 a, bf16x8 b, f32x16 c) {
  return __builtin_amdgcn_mfma_f32_32x32x16_bf16(a, b, c, 0, 0, 0);
}

DEVI uint32_t cvtpk(float lo, float hi) {
  uint32_t r;
  asm("v_cvt_pk_bf16_f32 %0, %1, %2" : "=v"(r) : "v"(lo), "v"(hi));
  return r;
}

DEVI f32x16 zero16() {
  f32x16 z;
#pragma unroll
  for (int i = 0; i < 16; ++i) z[i] = 0.f;
  return z;
}

// ---------------- cast f32 -> bf16 (8 els / thread) ----------------
__global__ __launch_bounds__(256) void k_cast(const float* __restrict__ in,
                                              bf16* __restrict__ out, int n8) {
  int i = blockIdx.x * 256 + threadIdx.x;
  if (i >= n8) return;
  const float4* p = (const float4*)in + (size_t)i * 2;
  float4 a = p[0], b = p[1];
  bf16x8 o;
  o[0] = (bf16)a.x; o[1] = (bf16)a.y; o[2] = (bf16)a.z; o[3] = (bf16)a.w;
  o[4] = (bf16)b.x; o[5] = (bf16)b.y; o[6] = (bf16)b.z; o[7] = (bf16)b.w;
  ((bf16x8*)out)[i] = o;
}

// ---------------- zero page (1 KiB) ----------------
__global__ void k_zero(float4* zp) {
  float4 z; z.x = z.y = z.z = z.w = 0.f;
  zp[threadIdx.x] = z;
}

// ---------------- GEMM C[M,N] = A[M,K] * W[N,K]^T  (bf16 in, f32 acc) ----------------
template <bool BF16_OUT>
DEVI void gemm_body(const bf16* __restrict__ A, const bf16* __restrict__ W,
                    void* __restrict__ Cout, int M, int N, int K) {
  __shared__ __align__(16) bf16 As[128 * 40];
  __shared__ __align__(16) bf16 Bs[128 * 40];
  const int tid = threadIdx.x;
  const int lane = tid & 63, wid = tid >> 6;
  const int l15 = lane & 15, g = lane >> 4;
  const int wm = wid >> 1, wn = wid & 1;
  const int bm0 = blockIdx.y * 128, bn0 = blockIdx.x * 128;

  f32x4 acc[4][4];
  for (int mi = 0; mi < 4; ++mi)
    for (int ni = 0; ni < 4; ++ni) {
      acc[mi][ni][0] = 0.f; acc[mi][ni][1] = 0.f;
      acc[mi][ni][2] = 0.f; acc[mi][ni][3] = 0.f;
    }

  const int nk = K >> 5;
  for (int kt = 0; kt < nk; ++kt) {
    const int k0 = kt << 5;
    for (int c = 0; c < 3; ++c) {
      int li = tid + (c << 8);
      if (li < 640) {
        int e0 = li << 3;
        int row = e0 / 40, col = e0 % 40;
        if (col >= 32) col = 24;
        gload_lds16(&A[(size_t)(bm0 + row) * K + k0 + col], As + (size_t)(li & ~63) * 8);
        gload_lds16(&W[(size_t)(bn0 + row) * K + k0 + col], Bs + (size_t)(li & ~63) * 8);
      }
    }
    __syncthreads();

    bf16x8 af[4], bfr[4];
    for (int mi = 0; mi < 4; ++mi)
      af[mi] = *(const bf16x8*)&As[(wm * 64 + mi * 16 + l15) * 40 + g * 8];
    for (int ni = 0; ni < 4; ++ni)
      bfr[ni] = *(const bf16x8*)&Bs[(wn * 64 + ni * 16 + l15) * 40 + g * 8];
    for (int mi = 0; mi < 4; ++mi)
      for (int ni = 0; ni < 4; ++ni)
        acc[mi][ni] = mfma16(af[mi], bfr[ni], acc[mi][ni]);
    __syncthreads();
  }

  for (int mi = 0; mi < 4; ++mi)
    for (int ni = 0; ni < 4; ++ni)
      for (int r = 0; r < 4; ++r) {
        int rowg = bm0 + wm * 64 + mi * 16 + g * 4 + r;
        int colg = bn0 + wn * 64 + ni * 16 + l15;
        float v = acc[mi][ni][r];
        if (BF16_OUT)
          ((bf16*)Cout)[(size_t)rowg * N + colg] = (bf16)v;
        else
          ((float*)Cout)[(size_t)rowg * N + colg] = v;
      }
}

__global__ __launch_bounds__(256) void k_gemm_qkv(
    const bf16* __restrict__ A, const bf16* __restrict__ Wq,
    const bf16* __restrict__ Wk, const bf16* __restrict__ Wv,
    bf16* __restrict__ q, bf16* __restrict__ k, bf16* __restrict__ v) {
  const bf16* W = (blockIdx.z == 0) ? Wq : (blockIdx.z == 1) ? Wk : Wv;
  bf16* out = (blockIdx.z == 0) ? q : (blockIdx.z == 1) ? k : v;
  gemm_body<true>(A, W, out, CBT, CD, CD);
}

__global__ __launch_bounds__(256) void k_gemm_out(
    const bf16* __restrict__ A, const bf16* __restrict__ W, float* __restrict__ out) {
  gemm_body<false>(A, W, out, CBT, CD, CD);
}

// ---------------- rotary, in place; q additionally scaled by HD^-0.5 ----------------
__global__ __launch_bounds__(256) void k_rotary(bf16* __restrict__ q, bf16* __restrict__ k,
                                                const float* __restrict__ cosb,
                                                const float* __restrict__ sinb) {
  const int bt = blockIdx.x;
  const int t = bt & (CT - 1);
  const size_t rowoff = (size_t)bt * CD;
  const float* cr = cosb + (size_t)t * CHD;
  const float* sr = sinb + (size_t)t * CHD;
  for (int i = threadIdx.x; i < 288; i += 256) {
    int tensor = i / 144;
    int rem = i - tensor * 144;
    int h = rem / 18, jg = rem % 18;
    int j = jg * 4;
    float scl = tensor ? 1.0f : 0.08333333333f;  // fold SCALE into q
    bf16* base = (tensor ? k : q) + rowoff + h * CHD;
    bf16x4 a = *(bf16x4*)&base[j];
    bf16x4 b2 = *(bf16x4*)&base[j + 72];
    f32x4 c1 = *(const f32x4*)&cr[j];
    f32x4 s1 = *(const f32x4*)&sr[j];
    f32x4 c2 = *(const f32x4*)&cr[j + 72];
    f32x4 s2 = *(const f32x4*)&sr[j + 72];
    bf16x4 o1, o2;
    for (int r = 0; r < 4; ++r) {
      float av = (float)a[r], bv = (float)b2[r];
      o1[r] = (bf16)((av * c1[r] - bv * s1[r]) * scl);
      o2[r] = (bf16)((bv * c2[r] + av * s2[r]) * scl);
    }
    *(bf16x4*)&base[j] = o1;
    *(bf16x4*)&base[j + 72] = o2;
  }
}

// ---------------- V transpose: v_lin[b][t][h*144+hd] -> vT[bh][hd][t] ----------------
__global__ __launch_bounds__(256) void k_vtrans(const bf16* __restrict__ v, bf16* __restrict__ vT) {
  __shared__ bf16 tile[64][152];
  const int bh = blockIdx.y;
  const int b = bh >> 3, h = bh & 7;
  const int t0 = blockIdx.x * 64;
  for (int i8 = threadIdx.x; i8 < 64 * 18; i8 += 256) {
    int r = i8 / 18, c8 = i8 % 18;
    *(bf16x8*)&tile[r][c8 * 8] =
        *(const bf16x8*)&v[((size_t)(b * CT + t0 + r)) * CD + h * CHD + c8 * 8];
  }
  __syncthreads();
  for (int o = threadIdx.x; o < CHD * 64; o += 256) {
    int hd = o / 64, j = o & 63;
    vT[((size_t)(bh * CHD + hd)) * CT + t0 + j] = tile[j][hd];
  }
}

// ---------------- P fragment builder: S^T C-regs -> PV B-frags, in-register ----------
DEVI void build_pfrag(const f32x16& s, float m, float& ps, bf16x8& f0, bf16x8& f1) {
  uint32_t pk[8];
#pragma unroll
  for (int a = 0; a < 8; ++a) {
    float p0 = exp2f((s[2 * a] - m) * LOG2E);
    float p1 = exp2f((s[2 * a + 1] - m) * LOG2E);
    ps += p0 + p1;
    pk[a] = cvtpk(p0, p1);
  }
  u32x2 r02 = __builtin_amdgcn_permlane32_swap(pk[0], pk[2], false, false);
  u32x2 r13 = __builtin_amdgcn_permlane32_swap(pk[1], pk[3], false, false);
  u32x2 r46 = __builtin_amdgcn_permlane32_swap(pk[4], pk[6], false, false);
  u32x2 r57 = __builtin_amdgcn_permlane32_swap(pk[5], pk[7], false, false);
  u32x4 w0 = {r02[0], r13[0], r02[1], r13[1]};
  u32x4 w1 = {r46[0], r57[0], r46[1], r57[1]};
  f0 = __builtin_bit_cast(bf16x8, w0);
  f1 = __builtin_bit_cast(bf16x8, w1);
}

// ---------------- flash attention, 32x32 MFMA, in-register P ----------------
// grid: (T/128, B*H). 4 waves x 32 q-rows. KV tile = 64.
// Ks: [64 keys][384B] (288B data, XOR-swizzled, 3x128B stride).
// Vs: [160 hd][128B]  (rows 144-159 zero, XOR-swizzled).
// S^T = mfma32(K, Q): lane owns q-col = lane&31 -> softmax lane-local.
// O^T = mfma32(V^T, P): P built in-register via cvt_pk + permlane32_swap.
__global__ __launch_bounds__(256, 2) void k_attn(const bf16* __restrict__ qg,
                                                 const bf16* __restrict__ kg,
                                                 const bf16* __restrict__ vT,
                                                 bf16* __restrict__ og,
                                                 const void* __restrict__ zp) {
  const int bh = blockIdx.y;
  const int b = bh >> 3, h = bh & 7;
  const int q0 = blockIdx.x << 7;
  const int tid = threadIdx.x, lane = tid & 63, wq = tid >> 6;
  const int l31 = lane & 31, hi = lane >> 5;
  const int hi16 = hi * 16;
  const int kxor = (l31 & 7) << 4;

  __shared__ __align__(16) bf16 Ks[64 * 192];   // 24576 B
  __shared__ __align__(16) bf16 Vs[160 * 64];   // 20480 B

  // Q fragments (B-frag: col=q=l31, k = ks*16 + hi*8 + e), 9 k-steps (144 = 9*16)
  bf16x8 qf[9];
  {
    const bf16* qbase = qg + (size_t)(b * CT + q0 + wq * 32 + l31) * CD + h * CHD + hi * 8;
#pragma unroll
    for (int ks = 0; ks < 9; ++ks) qf[ks] = *(const bf16x8*)&qbase[ks * 16];
  }

  // staging source precompute (pre-swizzled global source, LDS dest linear)
  const bf16* kp[6];
  const bf16* vp[5];
#pragma unroll
  for (int it = 0; it < 6; ++it) {
    int c = tid + it * 256;
    int row = c / 24, j = c - row * 24;
    int kcol = (j * 16) ^ ((row & 7) << 4);
    kp[it] = (kcol < 288) ? kg + (size_t)(b * CT + row) * CD + h * CHD + (kcol >> 1)
                          : (const bf16*)nullptr;
  }
#pragma unroll
  for (int it = 0; it < 5; ++it) {
    int c = tid + it * 256;
    int row = c >> 3;
    int col = ((c & 7) * 16) ^ ((row & 7) << 4);
    vp[it] = (row < CHD) ? vT + (size_t)(bh * CHD + row) * CT + (col >> 1)
                         : (const bf16*)nullptr;
  }

  f32x16 oacc[5];
#pragma unroll
  for (int t = 0; t < 5; ++t) oacc[t] = zero16();
  float mrow = -__builtin_inff();
  float lsum = 0.f;

  const char* kr0 = (const char*)Ks + (size_t)l31 * 384;
  const char* kr1 = kr0 + 32 * 384;

  for (int kv = 0; kv < CT; kv += 64) {
    __syncthreads();  // previous tile's reads done before overwrite
#pragma unroll
    for (int it = 0; it < 6; ++it)
      gload_lds16(kp[it] ? kp[it] + (size_t)kv * CD : zp,
                  Ks + ((size_t)(tid & ~63) + it * 256) * 8);
#pragma unroll
    for (int it = 0; it < 5; ++it)
      gload_lds16(vp[it] ? vp[it] + kv : zp,
                  Vs + ((size_t)(tid & ~63) + it * 256) * 8);
    __syncthreads();

    // S^T = K * Q^T : two 32-key tiles
    f32x16 s0 = zero16(), s1 = zero16();
#pragma unroll
    for (int ks = 0; ks < 9; ++ks) {
      int off = (ks * 32 + hi16) ^ kxor;
      s0 = mfma32(*(const bf16x8*)(kr0 + off), qf[ks], s0);
      s1 = mfma32(*(const bf16x8*)(kr1 + off), qf[ks], s1);
    }

    // online softmax (lane-local; partner lane^32 holds other 32 keys of same q)
    float mt = s0[0];
#pragma unroll
    for (int i = 1; i < 16; ++i) mt = fmaxf(mt, s0[i]);
#pragma unroll
    for (int i = 0; i < 16; ++i) mt = fmaxf(mt, s1[i]);
    mt = fmaxf(mt, __shfl_xor(mt, 32));

    if (mt > mrow + 5.5452f) {  // defer-max: rescale only on real growth (e^8 bound)
      float alpha = exp2f((mrow - mt) * LOG2E);
      lsum *= alpha;
#pragma unroll
      for (int t = 0; t < 5; ++t) oacc[t] = oacc[t] * alpha;
      mrow = mt;
    }

    float ps = 0.f;
    bf16x8 pf0, pf1, pf2, pf3;
    build_pfrag(s0, mrow, ps, pf0, pf1);
    build_pfrag(s1, mrow, ps, pf2, pf3);
    ps += __shfl_xor(ps, 32);
    lsum += ps;

    // O^T += V^T * P^T
#pragma unroll
    for (int t = 0; t < 5; ++t) {
      const char* vrow = (const char*)Vs + (size_t)(t * 32 + l31) * 128;
      oacc[t] = mfma32(*(const bf16x8*)(vrow + ((0 * 32 + hi16) ^ kxor)), pf0, oacc[t]);
      oacc[t] = mfma32(*(const bf16x8*)(vrow + ((1 * 32 + hi16) ^ kxor)), pf1, oacc[t]);
      oacc[t] = mfma32(*(const bf16x8*)(vrow + ((2 * 32 + hi16) ^ kxor)), pf2, oacc[t]);
      oacc[t] = mfma32(*(const bf16x8*)(vrow + ((3 * 32 + hi16) ^ kxor)), pf3, oacc[t]);
    }
  }

  // normalize + store: lane owns q-col = l31; C rows hd = t*32+(reg&3)+8*(reg>>2)+4*hi
  float inv = 1.0f / lsum;
  bf16* ob = og + (size_t)(b * CT + q0 + wq * 32 + l31) * CD + h * CHD;
#pragma unroll
  for (int t = 0; t < 5; ++t) {
#pragma unroll
    for (int pr = 0; pr < 8; ++pr) {
      if (t == 4 && pr >= 4) continue;  // hd >= 144 is pad
      int hd = t * 32 + ((2 * pr) & 3) + 8 * (pr >> 1) + 4 * hi;
      bf16x2 w;
      w[0] = (bf16)(oacc[t][2 * pr] * inv);
      w[1] = (bf16)(oacc[t][2 * pr + 1] * inv);
      *(bf16x2*)&ob[hd] = w;
    }
  }
}

// ---------------- launcher ----------------
extern "C" void kernel_launch(void* const* d_in, const int* in_sizes, int n_in,
                              void* d_out, int out_size, void* d_ws, size_t ws_size,
                              hipStream_t stream) {
  const float* x = (const float*)d_in[0];
  const float* cosb = (const float*)d_in[1];
  const float* sinb = (const float*)d_in[2];
  const float* Wq = (const float*)d_in[3];
  const float* Wk = (const float*)d_in[4];
  const float* Wv = (const float*)d_in[5];
  const float* Wo = (const float*)d_in[6];

  char* ws = (char*)d_ws;
  bf16* xb   = (bf16*)(ws + 0);           // reused as attention output (o_bt)
  bf16* wqb  = (bf16*)(ws + 18874368);
  bf16* wkb  = (bf16*)(ws + 21528576);
  bf16* wvb  = (bf16*)(ws + 24182784);
  bf16* wob  = (bf16*)(ws + 26836992);
  bf16* qlin = (bf16*)(ws + 29491200);
  bf16* klin = (bf16*)(ws + 48365568);
  bf16* vlin = (bf16*)(ws + 67239936);
  bf16* vT   = (bf16*)(ws + 86114304);
  void* zp   = (void*)(ws + 104988672);   // 1 KiB zero page

  k_zero<<<1, 64, 0, stream>>>((float4*)zp);

  // casts
  k_cast<<<4608, 256, 0, stream>>>(x, xb, CBT * CD / 8);
  k_cast<<<648, 256, 0, stream>>>(Wq, wqb, CD * CD / 8);
  k_cast<<<648, 256, 0, stream>>>(Wk, wkb, CD * CD / 8);
  k_cast<<<648, 256, 0, stream>>>(Wv, wvb, CD * CD / 8);
  k_cast<<<648, 256, 0, stream>>>(Wo, wob, CD * CD / 8);

  // QKV projections (fused over blockIdx.z)
  k_gemm_qkv<<<dim3(CD / 128, CBT / 128, 3), 256, 0, stream>>>(xb, wqb, wkb, wvb,
                                                               qlin, klin, vlin);
  // rotary in place on q,k (q scaled by HD^-0.5)
  k_rotary<<<CB * CT, 256, 0, stream>>>(qlin, klin, cosb, sinb);
  // V transpose
  k_vtrans<<<dim3(CT / 64, CB * CH), 256, 0, stream>>>(vlin, vT);
  // attention -> o (into xb region, [b][t][h*144+hd])
  k_attn<<<dim3(CT / 128, CB * CH), 256, 0, stream>>>(qlin, klin, vT, xb, zp);
  // output projection (f32 out)
  k_gemm_out<<<dim3(CD / 128, CBT / 128), 256, 0, stream>>>(xb, wob, (float*)d_out);
}

// Round 5
// 293.478 us; speedup vs baseline: 1.3903x; 1.0993x over previous
//
#include <hip/hip_runtime.h>
#include <cstdint>
#include <cstddef>

typedef __bf16 bf16;
typedef bf16 bf16x8 __attribute__((ext_vector_type(8)));
typedef bf16 bf16x4 __attribute__((ext_vector_type(4)));
typedef bf16 bf16x2 __attribute__((ext_vector_type(2)));
typedef float f32x4 __attribute__((ext_vector_type(4)));
typedef float f32x16 __attribute__((ext_vector_type(16)));
typedef uint32_t u32x2 __attribute__((ext_vector_type(2)));
typedef uint32_t u32x4 __attribute__((ext_vector_type(4)));

#define DEVI __device__ __forceinline__

// ---------------- constants ----------------
// B=4, T=2048, D=1152, H=8, HD=144, BT=8192
#define CB 4
#define CT 2048
#define CD 1152
#define CH 8
#define CHD 144
#define CBT 8192
#define LOG2E 1.44269504f

DEVI void gload_lds16(const void* g, void* l) {
  __builtin_amdgcn_global_load_lds(
      (const __attribute__((address_space(1))) void*)g,
      (__attribute__((address_space(3))) void*)l, 16, 0, 0);
}

DEVI f32x4 mfma16(bf16x8 a, bf16x8 b, f32x4 c) {
  return __builtin_amdgcn_mfma_f32_16x16x32_bf16(a, b, c, 0, 0, 0);
}
DEVI f32x16 mfma32(bf16x8 a, bf16x8 b, f32x16 c) {
  return __builtin_amdgcn_mfma_f32_32x32x16_bf16(a, b, c, 0, 0, 0);
}

DEVI uint32_t cvtpk(float lo, float hi) {
  uint32_t r;
  asm("v_cvt_pk_bf16_f32 %0, %1, %2" : "=v"(r) : "v"(lo), "v"(hi));
  return r;
}

DEVI f32x16 zero16() {
  f32x16 z;
#pragma unroll
  for (int i = 0; i < 16; ++i) z[i] = 0.f;
  return z;
}

// ---------------- cast f32 -> bf16 (8 els / thread) ----------------
__global__ __launch_bounds__(256) void k_cast(const float* __restrict__ in,
                                              bf16* __restrict__ out, int n8) {
  int i = blockIdx.x * 256 + threadIdx.x;
  if (i >= n8) return;
  const float4* p = (const float4*)in + (size_t)i * 2;
  float4 a = p[0], b = p[1];
  bf16x8 o;
  o[0] = (bf16)a.x; o[1] = (bf16)a.y; o[2] = (bf16)a.z; o[3] = (bf16)a.w;
  o[4] = (bf16)b.x; o[5] = (bf16)b.y; o[6] = (bf16)b.z; o[7] = (bf16)b.w;
  ((bf16x8*)out)[i] = o;
}

// 4 weight casts in one launch (blockIdx.y selects tensor)
__global__ __launch_bounds__(256) void k_cast4(
    const float* __restrict__ a, const float* __restrict__ b,
    const float* __restrict__ c, const float* __restrict__ d,
    bf16* __restrict__ oa, bf16* __restrict__ ob,
    bf16* __restrict__ oc, bf16* __restrict__ od, int n8) {
  int w = blockIdx.y;
  const float* in = (w == 0) ? a : (w == 1) ? b : (w == 2) ? c : d;
  bf16* out = (w == 0) ? oa : (w == 1) ? ob : (w == 2) ? oc : od;
  int i = blockIdx.x * 256 + threadIdx.x;
  if (i >= n8) return;
  const float4* p = (const float4*)in + (size_t)i * 2;
  float4 x = p[0], y = p[1];
  bf16x8 o;
  o[0] = (bf16)x.x; o[1] = (bf16)x.y; o[2] = (bf16)x.z; o[3] = (bf16)x.w;
  o[4] = (bf16)y.x; o[5] = (bf16)y.y; o[6] = (bf16)y.z; o[7] = (bf16)y.w;
  ((bf16x8*)out)[i] = o;
}

// ---------------- GEMM C[M,N] = A[M,K] * W[N,K]^T  (bf16 in, f32 acc) ----------------
// bm0/bn0 supplied by wrapper (XCD-swizzled).
template <bool BF16_OUT>
DEVI void gemm_body(const bf16* __restrict__ A, const bf16* __restrict__ W,
                    void* __restrict__ Cout, int M, int N, int K,
                    int bm0, int bn0) {
  __shared__ __align__(16) bf16 As[128 * 40];
  __shared__ __align__(16) bf16 Bs[128 * 40];
  const int tid = threadIdx.x;
  const int lane = tid & 63, wid = tid >> 6;
  const int l15 = lane & 15, g = lane >> 4;
  const int wm = wid >> 1, wn = wid & 1;

  f32x4 acc[4][4];
  for (int mi = 0; mi < 4; ++mi)
    for (int ni = 0; ni < 4; ++ni) {
      acc[mi][ni][0] = 0.f; acc[mi][ni][1] = 0.f;
      acc[mi][ni][2] = 0.f; acc[mi][ni][3] = 0.f;
    }

  const int nk = K >> 5;
  for (int kt = 0; kt < nk; ++kt) {
    const int k0 = kt << 5;
    for (int c = 0; c < 3; ++c) {
      int li = tid + (c << 8);
      if (li < 640) {
        int e0 = li << 3;
        int row = e0 / 40, col = e0 % 40;
        if (col >= 32) col = 24;
        gload_lds16(&A[(size_t)(bm0 + row) * K + k0 + col], As + (size_t)(li & ~63) * 8);
        gload_lds16(&W[(size_t)(bn0 + row) * K + k0 + col], Bs + (size_t)(li & ~63) * 8);
      }
    }
    __syncthreads();

    bf16x8 af[4], bfr[4];
    for (int mi = 0; mi < 4; ++mi)
      af[mi] = *(const bf16x8*)&As[(wm * 64 + mi * 16 + l15) * 40 + g * 8];
    for (int ni = 0; ni < 4; ++ni)
      bfr[ni] = *(const bf16x8*)&Bs[(wn * 64 + ni * 16 + l15) * 40 + g * 8];
    __builtin_amdgcn_s_setprio(1);
    for (int mi = 0; mi < 4; ++mi)
      for (int ni = 0; ni < 4; ++ni)
        acc[mi][ni] = mfma16(af[mi], bfr[ni], acc[mi][ni]);
    __builtin_amdgcn_s_setprio(0);
    __syncthreads();
  }

  for (int mi = 0; mi < 4; ++mi)
    for (int ni = 0; ni < 4; ++ni)
      for (int r = 0; r < 4; ++r) {
        int rowg = bm0 + wm * 64 + mi * 16 + g * 4 + r;
        int colg = bn0 + wn * 64 + ni * 16 + l15;
        float v = acc[mi][ni][r];
        if (BF16_OUT)
          ((bf16*)Cout)[(size_t)rowg * N + colg] = (bf16)v;
        else
          ((float*)Cout)[(size_t)rowg * N + colg] = v;
      }
}

__global__ __launch_bounds__(256) void k_gemm_qkv(
    const bf16* __restrict__ A, const bf16* __restrict__ Wq,
    const bf16* __restrict__ Wk, const bf16* __restrict__ Wv,
    bf16* __restrict__ q, bf16* __restrict__ k, bf16* __restrict__ v) {
  // T1 bijective XCD swizzle (nwg = 1728, %8 == 0)
  const int nx = gridDim.x, ny = gridDim.y;
  const int nwg = nx * ny * gridDim.z;
  const int orig = (blockIdx.z * ny + blockIdx.y) * nx + blockIdx.x;
  const int logical = (orig & 7) * (nwg >> 3) + (orig >> 3);
  const int lx = logical % nx;
  const int rest = logical / nx;
  const int ly = rest % ny, lz = rest / ny;
  const bf16* W = (lz == 0) ? Wq : (lz == 1) ? Wk : Wv;
  bf16* out = (lz == 0) ? q : (lz == 1) ? k : v;
  gemm_body<true>(A, W, out, CBT, CD, CD, ly * 128, lx * 128);
}

__global__ __launch_bounds__(256) void k_gemm_out(
    const bf16* __restrict__ A, const bf16* __restrict__ W, float* __restrict__ out) {
  const int nx = gridDim.x, ny = gridDim.y;
  const int nwg = nx * ny;
  const int orig = blockIdx.y * nx + blockIdx.x;
  const int logical = (orig & 7) * (nwg >> 3) + (orig >> 3);
  const int lx = logical % nx, ly = logical / nx;
  gemm_body<false>(A, W, out, CBT, CD, CD, ly * 128, lx * 128);
}

// ---------------- rotary, in place; q additionally scaled by HD^-0.5 ----------------
__global__ __launch_bounds__(256) void k_rotary(bf16* __restrict__ q, bf16* __restrict__ k,
                                                const float* __restrict__ cosb,
                                                const float* __restrict__ sinb) {
  const int bt = blockIdx.x;
  const int t = bt & (CT - 1);
  const size_t rowoff = (size_t)bt * CD;
  const float* cr = cosb + (size_t)t * CHD;
  const float* sr = sinb + (size_t)t * CHD;
  for (int i = threadIdx.x; i < 288; i += 256) {
    int tensor = i / 144;
    int rem = i - tensor * 144;
    int h = rem / 18, jg = rem % 18;
    int j = jg * 4;
    float scl = tensor ? 1.0f : 0.08333333333f;  // fold SCALE into q
    bf16* base = (tensor ? k : q) + rowoff + h * CHD;
    bf16x4 a = *(bf16x4*)&base[j];
    bf16x4 b2 = *(bf16x4*)&base[j + 72];
    f32x4 c1 = *(const f32x4*)&cr[j];
    f32x4 s1 = *(const f32x4*)&sr[j];
    f32x4 c2 = *(const f32x4*)&cr[j + 72];
    f32x4 s2 = *(const f32x4*)&sr[j + 72];
    bf16x4 o1, o2;
    for (int r = 0; r < 4; ++r) {
      float av = (float)a[r], bv = (float)b2[r];
      o1[r] = (bf16)((av * c1[r] - bv * s1[r]) * scl);
      o2[r] = (bf16)((bv * c2[r] + av * s2[r]) * scl);
    }
    *(bf16x4*)&base[j] = o1;
    *(bf16x4*)&base[j + 72] = o2;
  }
}

// ---------------- V transpose: v_lin[b][t][h*144+hd] -> vT[bh][hd][t] ----------------
__global__ __launch_bounds__(256) void k_vtrans(const bf16* __restrict__ v, bf16* __restrict__ vT) {
  __shared__ bf16 tile[64][152];
  const int bh = blockIdx.y;
  const int b = bh >> 3, h = bh & 7;
  const int t0 = blockIdx.x * 64;
  for (int i8 = threadIdx.x; i8 < 64 * 18; i8 += 256) {
    int r = i8 / 18, c8 = i8 % 18;
    *(bf16x8*)&tile[r][c8 * 8] =
        *(const bf16x8*)&v[((size_t)(b * CT + t0 + r)) * CD + h * CHD + c8 * 8];
  }
  __syncthreads();
  for (int o = threadIdx.x; o < CHD * 64; o += 256) {
    int hd = o / 64, j = o & 63;
    vT[((size_t)(bh * CHD + hd)) * CT + t0 + j] = tile[j][hd];
  }
}

// ---------------- P fragment builder: S^T C-regs -> PV B-frags, in-register ----------
DEVI void build_pfrag(const f32x16& s, float m, float& ps, bf16x8& f0, bf16x8& f1) {
  uint32_t pk[8];
#pragma unroll
  for (int a = 0; a < 8; ++a) {
    float p0 = exp2f((s[2 * a] - m) * LOG2E);
    float p1 = exp2f((s[2 * a + 1] - m) * LOG2E);
    ps += p0 + p1;
    pk[a] = cvtpk(p0, p1);
  }
  u32x2 r02 = __builtin_amdgcn_permlane32_swap(pk[0], pk[2], false, false);
  u32x2 r13 = __builtin_amdgcn_permlane32_swap(pk[1], pk[3], false, false);
  u32x2 r46 = __builtin_amdgcn_permlane32_swap(pk[4], pk[6], false, false);
  u32x2 r57 = __builtin_amdgcn_permlane32_swap(pk[5], pk[7], false, false);
  u32x4 w0 = {r02[0], r13[0], r02[1], r13[1]};
  u32x4 w1 = {r46[0], r57[0], r46[1], r57[1]};
  f0 = __builtin_bit_cast(bf16x8, w0);
  f1 = __builtin_bit_cast(bf16x8, w1);
}

// ---------------- flash attention, 32x32 MFMA, in-register P, async-staged ----------
// grid: (T/128, B*H). 4 waves x 32 q-rows. KV tile = 64, 32 tiles (CT/64).
// Ks: [64 keys][384B] (288B data, XOR-swizzled). Vs: [160 hd][128B] (rows 144+ zero).
// T14: next tile global->reg issued before compute; ds_write after barrier.
__global__ __launch_bounds__(256, 2) void k_attn(const bf16* __restrict__ qg,
                                                 const bf16* __restrict__ kg,
                                                 const bf16* __restrict__ vT,
                                                 bf16* __restrict__ og) {
  const int bh = blockIdx.y;
  const int b = bh >> 3, h = bh & 7;
  const int q0 = blockIdx.x << 7;
  const int tid = threadIdx.x, lane = tid & 63, wq = tid >> 6;
  const int l31 = lane & 31, hi = lane >> 5;
  const int hi16 = hi * 16;
  const int kxor = (l31 & 7) << 4;

  __shared__ __align__(16) bf16 Ks[64 * 192];   // 24576 B
  __shared__ __align__(16) bf16 Vs[160 * 64];   // 20480 B

  // Q fragments (B-frag: col=q=l31, k = ks*16 + hi*8 + e), 9 k-steps (144 = 9*16)
  bf16x8 qf[9];
  {
    const bf16* qbase = qg + (size_t)(b * CT + q0 + wq * 32 + l31) * CD + h * CHD + hi * 8;
#pragma unroll
    for (int ks = 0; ks < 9; ++ks) qf[ks] = *(const bf16x8*)&qbase[ks * 16];
  }

  // staging: linear global reads, swizzled LDS writes.
  // K: 64 rows x 18 chunks(16B) = 1152; V: 144 rows x 8 chunks = 1152.
  const bool ok4 = (tid < 128);
  const bf16* kgrow[5];
  const bf16* vgrow[5];
  bf16* kwp[5];
  bf16* vwp[5];
#pragma unroll
  for (int i = 0; i < 5; ++i) {
    int c = tid + i * 256;
    if (c >= 1152) c = 0;  // dead lanes (guarded at use)
    int row = c / 18, j = c - row * 18;
    kgrow[i] = kg + (size_t)(b * CT + row) * CD + h * CHD + j * 8;
    kwp[i] = Ks + row * 192 + ((((j * 16) ^ ((row & 7) << 4))) >> 1);
    int vr = c >> 3, vj = c & 7;
    vgrow[i] = vT + (size_t)(bh * CHD + vr) * CT + vj * 8;
    vwp[i] = Vs + vr * 64 + ((((vj * 16) ^ ((vr & 7) << 4))) >> 1);
  }

  // prologue: stage tile 0, zero V pad rows
  {
    u32x4 sk[5], sv[5];
#pragma unroll
    for (int i = 0; i < 5; ++i)
      if (i < 4 || ok4) { sk[i] = *(const u32x4*)kgrow[i]; sv[i] = *(const u32x4*)vgrow[i]; }
#pragma unroll
    for (int i = 0; i < 5; ++i)
      if (i < 4 || ok4) { *(u32x4*)kwp[i] = sk[i]; *(u32x4*)vwp[i] = sv[i]; }
    if (tid < 128) {
      u32x4 z = {0u, 0u, 0u, 0u};
      *(u32x4*)(Vs + (144 + (tid >> 3)) * 64 + (tid & 7) * 8) = z;
    }
  }
  __syncthreads();

  f32x16 oacc[5];
#pragma unroll
  for (int t = 0; t < 5; ++t) oacc[t] = zero16();
  float mrow = -__builtin_inff();
  float lsum = 0.f;

  const char* kr0 = (const char*)Ks + (size_t)l31 * 384;
  const char* kr1 = kr0 + 32 * 384;

  for (int t = 0; t < 32; ++t) {  // CT/64 = 32 KV tiles (r4 bug: was 16)
    // T14 issue-early: next tile's global loads (latency hides under compute)
    u32x4 sk[5], sv[5];
    if (t < 31) {
      const int kvn = (t + 1) << 6;
#pragma unroll
      for (int i = 0; i < 5; ++i)
        if (i < 4 || ok4) {
          sk[i] = *(const u32x4*)(kgrow[i] + (size_t)kvn * CD);
          sv[i] = *(const u32x4*)(vgrow[i] + kvn);
        }
    }

    // S^T = K * Q^T : two 32-key tiles
    f32x16 s0 = zero16(), s1 = zero16();
    __builtin_amdgcn_s_setprio(1);
#pragma unroll
    for (int ks = 0; ks < 9; ++ks) {
      int off = (ks * 32 + hi16) ^ kxor;
      s0 = mfma32(*(const bf16x8*)(kr0 + off), qf[ks], s0);
      s1 = mfma32(*(const bf16x8*)(kr1 + off), qf[ks], s1);
    }
    __builtin_amdgcn_s_setprio(0);

    // online softmax (lane-local; partner lane^32 holds other 32 keys of same q)
    float mt = s0[0];
#pragma unroll
    for (int i = 1; i < 16; ++i) mt = fmaxf(mt, s0[i]);
#pragma unroll
    for (int i = 0; i < 16; ++i) mt = fmaxf(mt, s1[i]);
    mt = fmaxf(mt, __shfl_xor(mt, 32));

    if (mt > mrow + 5.5452f) {  // defer-max
      float alpha = exp2f((mrow - mt) * LOG2E);
      lsum *= alpha;
#pragma unroll
      for (int u = 0; u < 5; ++u) oacc[u] = oacc[u] * alpha;
      mrow = mt;
    }

    float ps = 0.f;
    bf16x8 pf0, pf1, pf2, pf3;
    build_pfrag(s0, mrow, ps, pf0, pf1);
    build_pfrag(s1, mrow, ps, pf2, pf3);
    ps += __shfl_xor(ps, 32);
    lsum += ps;

    // O^T += V^T * P^T
    __builtin_amdgcn_s_setprio(1);
#pragma unroll
    for (int u = 0; u < 5; ++u) {
      const char* vrow = (const char*)Vs + (size_t)(u * 32 + l31) * 128;
      oacc[u] = mfma32(*(const bf16x8*)(vrow + ((0 * 32 + hi16) ^ kxor)), pf0, oacc[u]);
      oacc[u] = mfma32(*(const bf16x8*)(vrow + ((1 * 32 + hi16) ^ kxor)), pf1, oacc[u]);
      oacc[u] = mfma32(*(const bf16x8*)(vrow + ((2 * 32 + hi16) ^ kxor)), pf2, oacc[u]);
      oacc[u] = mfma32(*(const bf16x8*)(vrow + ((3 * 32 + hi16) ^ kxor)), pf3, oacc[u]);
    }
    __builtin_amdgcn_s_setprio(0);

    __syncthreads();  // all waves done reading tile t
    if (t < 31) {     // T14 write-late: commit next tile
#pragma unroll
      for (int i = 0; i < 5; ++i)
        if (i < 4 || ok4) { *(u32x4*)kwp[i] = sk[i]; *(u32x4*)vwp[i] = sv[i]; }
    }
    __syncthreads();  // writes visible
  }

  // normalize + store: lane owns q-col = l31; C rows hd = t*32+(reg&3)+8*(reg>>2)+4*hi
  float inv = 1.0f / lsum;
  bf16* ob = og + (size_t)(b * CT + q0 + wq * 32 + l31) * CD + h * CHD;
#pragma unroll
  for (int t = 0; t < 5; ++t) {
#pragma unroll
    for (int pr = 0; pr < 8; ++pr) {
      if (t == 4 && pr >= 4) continue;  // hd >= 144 is pad
      int hd = t * 32 + ((2 * pr) & 3) + 8 * (pr >> 1) + 4 * hi;
      bf16x2 w;
      w[0] = (bf16)(oacc[t][2 * pr] * inv);
      w[1] = (bf16)(oacc[t][2 * pr + 1] * inv);
      *(bf16x2*)&ob[hd] = w;
    }
  }
}

// ---------------- launcher ----------------
extern "C" void kernel_launch(void* const* d_in, const int* in_sizes, int n_in,
                              void* d_out, int out_size, void* d_ws, size_t ws_size,
                              hipStream_t stream) {
  const float* x = (const float*)d_in[0];
  const float* cosb = (const float*)d_in[1];
  const float* sinb = (const float*)d_in[2];
  const float* Wq = (const float*)d_in[3];
  const float* Wk = (const float*)d_in[4];
  const float* Wv = (const float*)d_in[5];
  const float* Wo = (const float*)d_in[6];

  char* ws = (char*)d_ws;
  bf16* xb   = (bf16*)(ws + 0);           // reused as attention output (o_bt)
  bf16* wqb  = (bf16*)(ws + 18874368);
  bf16* wkb  = (bf16*)(ws + 21528576);
  bf16* wvb  = (bf16*)(ws + 24182784);
  bf16* wob  = (bf16*)(ws + 26836992);
  bf16* qlin = (bf16*)(ws + 29491200);
  bf16* klin = (bf16*)(ws + 48365568);
  bf16* vlin = (bf16*)(ws + 67239936);
  bf16* vT   = (bf16*)(ws + 86114304);

  // casts
  k_cast<<<4608, 256, 0, stream>>>(x, xb, CBT * CD / 8);
  k_cast4<<<dim3(648, 4), 256, 0, stream>>>(Wq, Wk, Wv, Wo, wqb, wkb, wvb, wob,
                                            CD * CD / 8);

  // QKV projections (fused over z, XCD-swizzled)
  k_gemm_qkv<<<dim3(CD / 128, CBT / 128, 3), 256, 0, stream>>>(xb, wqb, wkb, wvb,
                                                               qlin, klin, vlin);
  // rotary in place on q,k (q scaled by HD^-0.5)
  k_rotary<<<CB * CT, 256, 0, stream>>>(qlin, klin, cosb, sinb);
  // V transpose
  k_vtrans<<<dim3(CT / 64, CB * CH), 256, 0, stream>>>(vlin, vT);
  // attention -> o (into xb region, [b][t][h*144+hd])
  k_attn<<<dim3(CT / 128, CB * CH), 256, 0, stream>>>(qlin, klin, vT, xb);
  // output projection (f32 out, XCD-swizzled)
  k_gemm_out<<<dim3(CD / 128, CBT / 128), 256, 0, stream>>>(xb, wob, (float*)d_out);
}

// Round 6
// 275.898 us; speedup vs baseline: 1.4789x; 1.0637x over previous
//
#include <hip/hip_runtime.h>
#include <cstdint>
#include <cstddef>

typedef __bf16 bf16;
typedef bf16 bf16x8 __attribute__((ext_vector_type(8)));
typedef bf16 bf16x4 __attribute__((ext_vector_type(4)));
typedef bf16 bf16x2 __attribute__((ext_vector_type(2)));
typedef float f32x4 __attribute__((ext_vector_type(4)));
typedef float f32x16 __attribute__((ext_vector_type(16)));
typedef uint32_t u32x2 __attribute__((ext_vector_type(2)));
typedef uint32_t u32x4 __attribute__((ext_vector_type(4)));

#define DEVI __device__ __forceinline__

// ---------------- constants ----------------
// B=4, T=2048, D=1152, H=8, HD=144, BT=8192
#define CB 4
#define CT 2048
#define CD 1152
#define CH 8
#define CHD 144
#define CBT 8192
#define LOG2E 1.44269504f

DEVI void gload_lds16(const void* g, void* l) {
  __builtin_amdgcn_global_load_lds(
      (const __attribute__((address_space(1))) void*)g,
      (__attribute__((address_space(3))) void*)l, 16, 0, 0);
}

DEVI f32x4 mfma16(bf16x8 a, bf16x8 b, f32x4 c) {
  return __builtin_amdgcn_mfma_f32_16x16x32_bf16(a, b, c, 0, 0, 0);
}
DEVI f32x16 mfma32(bf16x8 a, bf16x8 b, f32x16 c) {
  return __builtin_amdgcn_mfma_f32_32x32x16_bf16(a, b, c, 0, 0, 0);
}

DEVI uint32_t cvtpk(float lo, float hi) {
  uint32_t r;
  asm("v_cvt_pk_bf16_f32 %0, %1, %2" : "=v"(r) : "v"(lo), "v"(hi));
  return r;
}

DEVI f32x16 zero16() {
  f32x16 z;
#pragma unroll
  for (int i = 0; i < 16; ++i) z[i] = 0.f;
  return z;
}

// ---------------- cast f32 -> bf16 (8 els / thread) ----------------
__global__ __launch_bounds__(256) void k_cast(const float* __restrict__ in,
                                              bf16* __restrict__ out, int n8) {
  int i = blockIdx.x * 256 + threadIdx.x;
  if (i >= n8) return;
  const float4* p = (const float4*)in + (size_t)i * 2;
  float4 a = p[0], b = p[1];
  bf16x8 o;
  o[0] = (bf16)a.x; o[1] = (bf16)a.y; o[2] = (bf16)a.z; o[3] = (bf16)a.w;
  o[4] = (bf16)b.x; o[5] = (bf16)b.y; o[6] = (bf16)b.z; o[7] = (bf16)b.w;
  ((bf16x8*)out)[i] = o;
}

// 4 weight casts in one launch (blockIdx.y selects tensor)
__global__ __launch_bounds__(256) void k_cast4(
    const float* __restrict__ a, const float* __restrict__ b,
    const float* __restrict__ c, const float* __restrict__ d,
    bf16* __restrict__ oa, bf16* __restrict__ ob,
    bf16* __restrict__ oc, bf16* __restrict__ od, int n8) {
  int w = blockIdx.y;
  const float* in = (w == 0) ? a : (w == 1) ? b : (w == 2) ? c : d;
  bf16* out = (w == 0) ? oa : (w == 1) ? ob : (w == 2) ? oc : od;
  int i = blockIdx.x * 256 + threadIdx.x;
  if (i >= n8) return;
  const float4* p = (const float4*)in + (size_t)i * 2;
  float4 x = p[0], y = p[1];
  bf16x8 o;
  o[0] = (bf16)x.x; o[1] = (bf16)x.y; o[2] = (bf16)x.z; o[3] = (bf16)x.w;
  o[4] = (bf16)y.x; o[5] = (bf16)y.y; o[6] = (bf16)y.z; o[7] = (bf16)y.w;
  ((bf16x8*)out)[i] = o;
}

// ---------------- GEMM C[M,N] = A[M,K] * W[N,K]^T  (bf16 in, f32 acc) ----------------
// bm0/bn0 supplied by wrapper (XCD-swizzled).
template <bool BF16_OUT>
DEVI void gemm_body(const bf16* __restrict__ A, const bf16* __restrict__ W,
                    void* __restrict__ Cout, int M, int N, int K,
                    int bm0, int bn0) {
  __shared__ __align__(16) bf16 As[128 * 40];
  __shared__ __align__(16) bf16 Bs[128 * 40];
  const int tid = threadIdx.x;
  const int lane = tid & 63, wid = tid >> 6;
  const int l15 = lane & 15, g = lane >> 4;
  const int wm = wid >> 1, wn = wid & 1;

  f32x4 acc[4][4];
  for (int mi = 0; mi < 4; ++mi)
    for (int ni = 0; ni < 4; ++ni) {
      acc[mi][ni][0] = 0.f; acc[mi][ni][1] = 0.f;
      acc[mi][ni][2] = 0.f; acc[mi][ni][3] = 0.f;
    }

  const int nk = K >> 5;
  for (int kt = 0; kt < nk; ++kt) {
    const int k0 = kt << 5;
    for (int c = 0; c < 3; ++c) {
      int li = tid + (c << 8);
      if (li < 640) {
        int e0 = li << 3;
        int row = e0 / 40, col = e0 % 40;
        if (col >= 32) col = 24;
        gload_lds16(&A[(size_t)(bm0 + row) * K + k0 + col], As + (size_t)(li & ~63) * 8);
        gload_lds16(&W[(size_t)(bn0 + row) * K + k0 + col], Bs + (size_t)(li & ~63) * 8);
      }
    }
    __syncthreads();

    bf16x8 af[4], bfr[4];
    for (int mi = 0; mi < 4; ++mi)
      af[mi] = *(const bf16x8*)&As[(wm * 64 + mi * 16 + l15) * 40 + g * 8];
    for (int ni = 0; ni < 4; ++ni)
      bfr[ni] = *(const bf16x8*)&Bs[(wn * 64 + ni * 16 + l15) * 40 + g * 8];
    __builtin_amdgcn_s_setprio(1);
    for (int mi = 0; mi < 4; ++mi)
      for (int ni = 0; ni < 4; ++ni)
        acc[mi][ni] = mfma16(af[mi], bfr[ni], acc[mi][ni]);
    __builtin_amdgcn_s_setprio(0);
    __syncthreads();
  }

  for (int mi = 0; mi < 4; ++mi)
    for (int ni = 0; ni < 4; ++ni)
      for (int r = 0; r < 4; ++r) {
        int rowg = bm0 + wm * 64 + mi * 16 + g * 4 + r;
        int colg = bn0 + wn * 64 + ni * 16 + l15;
        float v = acc[mi][ni][r];
        if (BF16_OUT)
          ((bf16*)Cout)[(size_t)rowg * N + colg] = (bf16)v;
        else
          ((float*)Cout)[(size_t)rowg * N + colg] = v;
      }
}

__global__ __launch_bounds__(256) void k_gemm_qkv(
    const bf16* __restrict__ A, const bf16* __restrict__ Wq,
    const bf16* __restrict__ Wk, const bf16* __restrict__ Wv,
    bf16* __restrict__ q, bf16* __restrict__ k, bf16* __restrict__ v) {
  // T1 bijective XCD swizzle (nwg = 1728, %8 == 0)
  const int nx = gridDim.x, ny = gridDim.y;
  const int nwg = nx * ny * gridDim.z;
  const int orig = (blockIdx.z * ny + blockIdx.y) * nx + blockIdx.x;
  const int logical = (orig & 7) * (nwg >> 3) + (orig >> 3);
  const int lx = logical % nx;
  const int rest = logical / nx;
  const int ly = rest % ny, lz = rest / ny;
  const bf16* W = (lz == 0) ? Wq : (lz == 1) ? Wk : Wv;
  bf16* out = (lz == 0) ? q : (lz == 1) ? k : v;
  gemm_body<true>(A, W, out, CBT, CD, CD, ly * 128, lx * 128);
}

__global__ __launch_bounds__(256) void k_gemm_out(
    const bf16* __restrict__ A, const bf16* __restrict__ W, float* __restrict__ out) {
  const int nx = gridDim.x, ny = gridDim.y;
  const int nwg = nx * ny;
  const int orig = blockIdx.y * nx + blockIdx.x;
  const int logical = (orig & 7) * (nwg >> 3) + (orig >> 3);
  const int lx = logical % nx, ly = logical / nx;
  gemm_body<false>(A, W, out, CBT, CD, CD, ly * 128, lx * 128);
}

// ---------------- rotary, in place; q additionally scaled by HD^-0.5 ----------------
__global__ __launch_bounds__(256) void k_rotary(bf16* __restrict__ q, bf16* __restrict__ k,
                                                const float* __restrict__ cosb,
                                                const float* __restrict__ sinb) {
  const int bt = blockIdx.x;
  const int t = bt & (CT - 1);
  const size_t rowoff = (size_t)bt * CD;
  const float* cr = cosb + (size_t)t * CHD;
  const float* sr = sinb + (size_t)t * CHD;
  for (int i = threadIdx.x; i < 288; i += 256) {
    int tensor = i / 144;
    int rem = i - tensor * 144;
    int h = rem / 18, jg = rem % 18;
    int j = jg * 4;
    float scl = tensor ? 1.0f : 0.08333333333f;  // fold SCALE into q
    bf16* base = (tensor ? k : q) + rowoff + h * CHD;
    bf16x4 a = *(bf16x4*)&base[j];
    bf16x4 b2 = *(bf16x4*)&base[j + 72];
    f32x4 c1 = *(const f32x4*)&cr[j];
    f32x4 s1 = *(const f32x4*)&sr[j];
    f32x4 c2 = *(const f32x4*)&cr[j + 72];
    f32x4 s2 = *(const f32x4*)&sr[j + 72];
    bf16x4 o1, o2;
    for (int r = 0; r < 4; ++r) {
      float av = (float)a[r], bv = (float)b2[r];
      o1[r] = (bf16)((av * c1[r] - bv * s1[r]) * scl);
      o2[r] = (bf16)((bv * c2[r] + av * s2[r]) * scl);
    }
    *(bf16x4*)&base[j] = o1;
    *(bf16x4*)&base[j + 72] = o2;
  }
}

// ---------------- V transpose: v_lin[b][t][h*144+hd] -> vT[bh][hd][t] ----------------
__global__ __launch_bounds__(256) void k_vtrans(const bf16* __restrict__ v, bf16* __restrict__ vT) {
  __shared__ bf16 tile[64][152];
  const int bh = blockIdx.y;
  const int b = bh >> 3, h = bh & 7;
  const int t0 = blockIdx.x * 64;
  for (int i8 = threadIdx.x; i8 < 64 * 18; i8 += 256) {
    int r = i8 / 18, c8 = i8 % 18;
    *(bf16x8*)&tile[r][c8 * 8] =
        *(const bf16x8*)&v[((size_t)(b * CT + t0 + r)) * CD + h * CHD + c8 * 8];
  }
  __syncthreads();
  for (int o = threadIdx.x; o < CHD * 64; o += 256) {
    int hd = o / 64, j = o & 63;
    vT[((size_t)(bh * CHD + hd)) * CT + t0 + j] = tile[j][hd];
  }
}

// ---------------- P fragment builder: S^T C-regs -> PV B-frags, in-register ----------
DEVI void build_pfrag(const f32x16& s, float m, float& ps, bf16x8& f0, bf16x8& f1) {
  uint32_t pk[8];
#pragma unroll
  for (int a = 0; a < 8; ++a) {
    float p0 = exp2f((s[2 * a] - m) * LOG2E);
    float p1 = exp2f((s[2 * a + 1] - m) * LOG2E);
    ps += p0 + p1;
    pk[a] = cvtpk(p0, p1);
  }
  u32x2 r02 = __builtin_amdgcn_permlane32_swap(pk[0], pk[2], false, false);
  u32x2 r13 = __builtin_amdgcn_permlane32_swap(pk[1], pk[3], false, false);
  u32x2 r46 = __builtin_amdgcn_permlane32_swap(pk[4], pk[6], false, false);
  u32x2 r57 = __builtin_amdgcn_permlane32_swap(pk[5], pk[7], false, false);
  u32x4 w0 = {r02[0], r13[0], r02[1], r13[1]};
  u32x4 w1 = {r46[0], r57[0], r46[1], r57[1]};
  f0 = __builtin_bit_cast(bf16x8, w0);
  f1 = __builtin_bit_cast(bf16x8, w1);
}

// ---------------- flash attention: 2-phase double-buffered gload_lds pipeline ------
// grid: 256 blocks (bh-XCD affinity), 512 threads = 8 waves x 32 q-rows (256 q/block).
// Ks[2][64][384B] (288B data, XOR-swizzled via pre-swizzled source, 3x128B stride).
// Vs[2][160][128B] (rows 144-159 zero, staged once). KV tile = 64 keys, 32 tiles.
// Per tile: issue gload_lds for t+1 into buf^1; compute from buf; single barrier.
__global__ __launch_bounds__(512, 2) void k_attn(const bf16* __restrict__ qg,
                                                 const bf16* __restrict__ kg,
                                                 const bf16* __restrict__ vT,
                                                 bf16* __restrict__ og) {
  const int lin = blockIdx.x;
  const int xcd = lin & 7, idx = lin >> 3;
  const int bh = ((idx & 3) << 3) | xcd;   // 4 heads per XCD -> K/V L2-resident
  const int qx = idx >> 2;
  const int b = bh >> 3, h = bh & 7;
  const int q0 = qx << 8;
  const int tid = threadIdx.x, lane = tid & 63, wq = tid >> 6;
  const int l31 = lane & 31, hi = lane >> 5;
  const int hi16 = hi * 16;
  const int kxor = (l31 & 7) << 4;

  constexpr int KBUF = 64 * 192;    // 12288 els = 24576 B
  constexpr int VBUF = 160 * 64;    // 10240 els = 20480 B
  __shared__ __align__(16) bf16 Ks[2 * KBUF];   // 49152 B
  __shared__ __align__(16) bf16 Vs[2 * VBUF];   // 40960 B  (total 90112 B)

  // Q fragments (B-frag: col=q=l31, k = ks*16 + hi*8 + e), 9 k-steps (144 = 9*16)
  bf16x8 qf[9];
  {
    const bf16* qbase = qg + (size_t)(b * CT + q0 + wq * 32 + l31) * CD + h * CHD + hi * 8;
#pragma unroll
    for (int ks = 0; ks < 9; ++ks) qf[ks] = *(const bf16x8*)&qbase[ks * 16];
  }

  // staging precompute: LDS dest linear, global source pre-swizzled (m173 pattern).
  // K: 64 rows x 24 chunks = 1536 = 3*512; V: 144 rows x 8 chunks = 1152 (it2: tid<128).
  const bf16* ksrc[3];
  const bf16* vsrc[3];
  int kldo[3], vldo[3];
#pragma unroll
  for (int it = 0; it < 3; ++it) {
    int c = tid + it * 512;
    int krow = c / 24, kj = c - krow * 24;
    int kcol = (kj * 16) ^ ((krow & 7) << 4);
    if (kcol >= 288) kcol = 0;  // pad slot: load garbage from a valid addr (never read)
    ksrc[it] = kg + (size_t)(b * CT + krow) * CD + h * CHD + (kcol >> 1);
    kldo[it] = ((tid & ~63) + it * 512) * 8;
    int vr = c >> 3, vj = c & 7;
    int vcol = (vj * 16) ^ ((vr & 7) << 4);
    if (vr > 143) vr = 143;  // it2 tail unused (guarded), keep ptr valid
    vsrc[it] = vT + (size_t)(bh * CHD + vr) * CT + (vcol >> 1);
    vldo[it] = ((tid & ~63) + it * 512) * 8;
  }
  const bool vok2 = (tid < 128);  // wave-uniform guard for V chunk set #2

  // zero V pad rows (144..159) in BOTH buffers — staged loads never touch them
  if (tid < 256) {
    u32x4 z = {0u, 0u, 0u, 0u};
    int bsel = tid >> 7, off = tid & 127;
    *(u32x4*)(Vs + bsel * VBUF + 144 * 64 + off * 8) = z;
  }

  // prologue: stage tile 0 into buf 0
  {
    bf16* Kc = Ks;
    bf16* Vc = Vs;
#pragma unroll
    for (int it = 0; it < 3; ++it) gload_lds16(ksrc[it], Kc + kldo[it]);
#pragma unroll
    for (int it = 0; it < 2; ++it) gload_lds16(vsrc[it], Vc + vldo[it]);
    if (vok2) gload_lds16(vsrc[2], Vc + vldo[2]);
  }
  __syncthreads();  // drains vmcnt(0): tile 0 staged, pad zeros visible

  f32x16 oacc[5];
#pragma unroll
  for (int t = 0; t < 5; ++t) oacc[t] = zero16();
  float mrow = -__builtin_inff();
  float lsum = 0.f;

  int cur = 0;
  for (int t = 0; t < 32; ++t) {
    bf16* Kc = Ks + cur * KBUF;
    bf16* Vc = Vs + cur * VBUF;

    // T3 issue-early: stage tile t+1 into the other buffer (no wait here)
    if (t < 31) {
      bf16* Kn = Ks + (cur ^ 1) * KBUF;
      bf16* Vn = Vs + (cur ^ 1) * VBUF;
      const int kvn = (t + 1) << 6;
#pragma unroll
      for (int it = 0; it < 3; ++it) gload_lds16(ksrc[it] + (size_t)kvn * CD, Kn + kldo[it]);
#pragma unroll
      for (int it = 0; it < 2; ++it) gload_lds16(vsrc[it] + kvn, Vn + vldo[it]);
      if (vok2) gload_lds16(vsrc[2] + kvn, Vn + vldo[2]);
    }
    __builtin_amdgcn_sched_barrier(0);  // pin stage issue before compute

    // S^T = K * Q^T : two 32-key tiles
    const char* kr0 = (const char*)Kc + (size_t)l31 * 384;
    const char* kr1 = kr0 + 32 * 384;
    f32x16 s0 = zero16(), s1 = zero16();
    __builtin_amdgcn_s_setprio(1);
#pragma unroll
    for (int ks = 0; ks < 9; ++ks) {
      int off = (ks * 32 + hi16) ^ kxor;
      s0 = mfma32(*(const bf16x8*)(kr0 + off), qf[ks], s0);
      s1 = mfma32(*(const bf16x8*)(kr1 + off), qf[ks], s1);
    }
    __builtin_amdgcn_s_setprio(0);

    // online softmax (lane-local; partner lane^32 holds other 32 keys of same q)
    float mt = s0[0];
#pragma unroll
    for (int i = 1; i < 16; ++i) mt = fmaxf(mt, s0[i]);
#pragma unroll
    for (int i = 0; i < 16; ++i) mt = fmaxf(mt, s1[i]);
    mt = fmaxf(mt, __shfl_xor(mt, 32));

    if (mt > mrow + 5.5452f) {  // defer-max (P bounded by e^5.55=256)
      float alpha = exp2f((mrow - mt) * LOG2E);
      lsum *= alpha;
#pragma unroll
      for (int u = 0; u < 5; ++u) oacc[u] = oacc[u] * alpha;
      mrow = mt;
    }

    float ps = 0.f;
    bf16x8 pf0, pf1, pf2, pf3;
    build_pfrag(s0, mrow, ps, pf0, pf1);
    build_pfrag(s1, mrow, ps, pf2, pf3);
    ps += __shfl_xor(ps, 32);
    lsum += ps;

    // O^T += V^T * P^T
    __builtin_amdgcn_s_setprio(1);
#pragma unroll
    for (int u = 0; u < 5; ++u) {
      const char* vrow = (const char*)Vc + (size_t)(u * 32 + l31) * 128;
      oacc[u] = mfma32(*(const bf16x8*)(vrow + ((0 * 32 + hi16) ^ kxor)), pf0, oacc[u]);
      oacc[u] = mfma32(*(const bf16x8*)(vrow + ((1 * 32 + hi16) ^ kxor)), pf1, oacc[u]);
      oacc[u] = mfma32(*(const bf16x8*)(vrow + ((2 * 32 + hi16) ^ kxor)), pf2, oacc[u]);
      oacc[u] = mfma32(*(const bf16x8*)(vrow + ((3 * 32 + hi16) ^ kxor)), pf3, oacc[u]);
    }
    __builtin_amdgcn_s_setprio(0);

    __syncthreads();  // reads of buf[cur] done + my prefetch drained (vmcnt 0)
    cur ^= 1;
  }

  // normalize + store: lane owns q-col = l31; C rows hd = u*32+(reg&3)+8*(reg>>2)+4*hi
  float inv = 1.0f / lsum;
  bf16* ob = og + (size_t)(b * CT + q0 + wq * 32 + l31) * CD + h * CHD;
#pragma unroll
  for (int u = 0; u < 5; ++u) {
#pragma unroll
    for (int pr = 0; pr < 8; ++pr) {
      if (u == 4 && pr >= 4) continue;  // hd >= 144 is pad
      int hd = u * 32 + ((2 * pr) & 3) + 8 * (pr >> 1) + 4 * hi;
      bf16x2 w;
      w[0] = (bf16)(oacc[u][2 * pr] * inv);
      w[1] = (bf16)(oacc[u][2 * pr + 1] * inv);
      *(bf16x2*)&ob[hd] = w;
    }
  }
}

// ---------------- launcher ----------------
extern "C" void kernel_launch(void* const* d_in, const int* in_sizes, int n_in,
                              void* d_out, int out_size, void* d_ws, size_t ws_size,
                              hipStream_t stream) {
  const float* x = (const float*)d_in[0];
  const float* cosb = (const float*)d_in[1];
  const float* sinb = (const float*)d_in[2];
  const float* Wq = (const float*)d_in[3];
  const float* Wk = (const float*)d_in[4];
  const float* Wv = (const float*)d_in[5];
  const float* Wo = (const float*)d_in[6];

  char* ws = (char*)d_ws;
  bf16* xb   = (bf16*)(ws + 0);           // reused as attention output (o_bt)
  bf16* wqb  = (bf16*)(ws + 18874368);
  bf16* wkb  = (bf16*)(ws + 21528576);
  bf16* wvb  = (bf16*)(ws + 24182784);
  bf16* wob  = (bf16*)(ws + 26836992);
  bf16* qlin = (bf16*)(ws + 29491200);
  bf16* klin = (bf16*)(ws + 48365568);
  bf16* vlin = (bf16*)(ws + 67239936);
  bf16* vT   = (bf16*)(ws + 86114304);

  // casts
  k_cast<<<4608, 256, 0, stream>>>(x, xb, CBT * CD / 8);
  k_cast4<<<dim3(648, 4), 256, 0, stream>>>(Wq, Wk, Wv, Wo, wqb, wkb, wvb, wob,
                                            CD * CD / 8);

  // QKV projections (fused over z, XCD-swizzled)
  k_gemm_qkv<<<dim3(CD / 128, CBT / 128, 3), 256, 0, stream>>>(xb, wqb, wkb, wvb,
                                                               qlin, klin, vlin);
  // rotary in place on q,k (q scaled by HD^-0.5)
  k_rotary<<<CB * CT, 256, 0, stream>>>(qlin, klin, cosb, sinb);
  // V transpose
  k_vtrans<<<dim3(CT / 64, CB * CH), 256, 0, stream>>>(vlin, vT);
  // attention -> o (into xb region, [b][t][h*144+hd])
  k_attn<<<256, 512, 0, stream>>>(qlin, klin, vT, xb);
  // output projection (f32 out, XCD-swizzled)
  k_gemm_out<<<dim3(CD / 128, CBT / 128), 256, 0, stream>>>(xb, wob, (float*)d_out);
}